// Round 2
// 472.805 us; speedup vs baseline: 1.0058x; 1.0058x over previous
//
#include <hip/hip_runtime.h>

// ConvCaps: votes[b,h,w,ky,kx,i,o,m,n] = poses[b,h+ky,w+kx,i,m,n] * pk[ky,kx,i,o,m,n]
//           act_out[b,h,w,ky,kx,i]     = activations[b,h+ky,w+kx,i]
// Shapes: poses (4,16,16,32,4,4) f32, activations (4,16,16,32,1,1) f32,
//         pose_kernel (3,3,32,32,4,4) f32.  oh=ow=14 (VALID, stride 1).
// Output flat: votes (115,605,504 f32 = 28,901,376 float4) then act_out (225,792 f32).
//
// Structure: one block per output "slot" (b,h,w,ky,kx) — 4*14*14*3*3 = 7056 slots.
// Each slot owns a contiguous 4096-float4 (64 KB) vote chunk (i*128 + o*4 + e4)
// plus 8 act float4s. Slot decode (div/mod 3,3,14,14) runs ONCE per block on the
// scalar path; the 16-deep per-thread loop is shift/mask only. This cuts wave count
// 452k -> 28k vs. the 1-float4-per-thread version, amortizing wave prologue that
// was starving the store pipe (~2.6 TB/s effective vs 6.1 TB/s fill-kernel proof).
//
// v4f (clang ext_vector_type) instead of HIP float4: __builtin_nontemporal_store
// requires a native vector type.

typedef float v4f __attribute__((ext_vector_type(4)));

#define SLOTS    7056u       // 4*14*14*3*3
#define V4_COUNT 28901376u   // votes float4s: 7056 * 4096
#define A4_COUNT 56448u      // act float4s:   7056 * 8

__global__ __launch_bounds__(256) void convcaps_kernel(
    const v4f* __restrict__ poses,   // (4,16,16,32*4=128 v4f per pixel)
    const v4f* __restrict__ acts,    // (4,16,16, 8 v4f per pixel)
    const v4f* __restrict__ pk,      // (3,3, 4096 v4f per (ky,kx))
    v4f* __restrict__ out) {

    const unsigned blk = blockIdx.x;
    const unsigned t   = threadIdx.x;

    // Decode slot = (((b*14+h)*14+w)*3+ky)*3+kx  -- uniform, once per block.
    unsigned r  = blk;
    unsigned kx = r % 3u;  r /= 3u;
    unsigned ky = r % 3u;  r /= 3u;
    unsigned w  = r % 14u; r /= 14u;
    unsigned h  = r % 14u; r /= 14u;
    unsigned b  = r;

    const unsigned src_pix = (b * 16u + h + ky) * 16u + (w + kx);
    const v4f* __restrict__ pbase = poses + (size_t)src_pix * 128u;          // [i*4 + e4]
    const v4f* __restrict__ kbase = pk    + (size_t)(ky * 3u + kx) * 4096u;  // [(i*32+o)*4 + e4]
    v4f* __restrict__ obase       = out   + (size_t)blk * 4096u;

    // Per-thread invariants: e4, o fixed; i walks i0, i0+2, ..., i0+30.
    const unsigned e4 = t & 3u;
    const unsigned o  = (t >> 2) & 31u;
    const unsigned i0 = t >> 7;          // 0 or 1

    #pragma unroll
    for (unsigned it = 0; it < 16u; ++it) {
        const unsigned i = i0 + 2u * it;
        v4f p = pbase[i * 4u + e4];                  // 64B broadcast per wave (L1)
        v4f k = kbase[(i * 32u + o) * 4u + e4];      // 1KB coalesced per wave (L1/L2)
        v4f v = p * k;
        __builtin_nontemporal_store(v, &obase[it * 256u + t]);  // streaming store
    }

    // Act passthrough: 8 v4fs per slot, same slot ordering.
    if (t < 8u) {
        v4f a = acts[(size_t)src_pix * 8u + t];
        __builtin_nontemporal_store(a, &out[V4_COUNT + blk * 8u + t]);
    }
}

extern "C" void kernel_launch(void* const* d_in, const int* in_sizes, int n_in,
                              void* d_out, int out_size, void* d_ws, size_t ws_size,
                              hipStream_t stream) {
    const v4f* poses = (const v4f*)d_in[0];
    const v4f* acts  = (const v4f*)d_in[1];
    const v4f* pk    = (const v4f*)d_in[2];
    v4f* out         = (v4f*)d_out;

    convcaps_kernel<<<SLOTS, 256, 0, stream>>>(poses, acts, pk, out);
}